// Round 3
// baseline (308.142 us; speedup 1.0000x reference)
//
#include <hip/hip_runtime.h>
#include <hip/hip_bf16.h>
#include <stdint.h>

typedef __bf16 bf16x8_t __attribute__((ext_vector_type(8)));
typedef float f32x4 __attribute__((ext_vector_type(4)));

__device__ __forceinline__ unsigned short f2bf_rne(float f) {
  unsigned int u = __float_as_uint(f);
  u += 0x7FFFu + ((u >> 16) & 1u);
  return (unsigned short)(u >> 16);
}

// ---------- kernel 1: alpha[o] = mean|W[o,:]|, wb[o,:] = sign(W[o,:]) as bf16 bits
__global__ __launch_bounds__(256) void k_prep_w(const float* __restrict__ W,
                                                unsigned short* __restrict__ wb,
                                                float* __restrict__ alpha, int K) {
  const int o = blockIdx.x;
  const float* row = W + (size_t)o * K;
  unsigned short* orow = wb + (size_t)o * K;
  const int tid = threadIdx.x;
  float s = 0.f;
  const int nj = K / 1024;
  for (int j = 0; j < nj; ++j) {
    int base = j * 1024 + tid * 4;
    float4 v = *reinterpret_cast<const float4*>(row + base);
    s += fabsf(v.x) + fabsf(v.y) + fabsf(v.z) + fabsf(v.w);
    ushort4 sg;
    sg.x = v.x > 0.f ? 0x3F80u : (v.x < 0.f ? 0xBF80u : 0u);
    sg.y = v.y > 0.f ? 0x3F80u : (v.y < 0.f ? 0xBF80u : 0u);
    sg.z = v.z > 0.f ? 0x3F80u : (v.z < 0.f ? 0xBF80u : 0u);
    sg.w = v.w > 0.f ? 0x3F80u : (v.w < 0.f ? 0xBF80u : 0u);
    *reinterpret_cast<ushort4*>(orow + base) = sg;
  }
  for (int off = 32; off > 0; off >>= 1) s += __shfl_down(s, off);
  __shared__ float red[4];
  int lane = tid & 63, wid = tid >> 6;
  if (lane == 0) red[wid] = s;
  __syncthreads();
  if (tid == 0) alpha[o] = (red[0] + red[1] + red[2] + red[3]) / (float)K;
}

// ---------- kernel 2: x fp32 -> bf16 (RNE)
__global__ __launch_bounds__(256) void k_conv_x(const float* __restrict__ x,
                                                unsigned short* __restrict__ xb,
                                                long long n4) {
  long long i = (long long)blockIdx.x * blockDim.x + threadIdx.x;
  const long long stride = (long long)gridDim.x * blockDim.x;
  for (; i < n4; i += stride) {
    float4 v = reinterpret_cast<const float4*>(x)[i];
    ushort4 o;
    o.x = f2bf_rne(v.x);
    o.y = f2bf_rne(v.y);
    o.z = f2bf_rne(v.z);
    o.w = f2bf_rne(v.w);
    reinterpret_cast<ushort4*>(xb)[i] = o;
  }
}

#define GLDS(gp, lp)                                                                   \
  __builtin_amdgcn_global_load_lds((const __attribute__((address_space(1))) void*)(gp),\
                                   (__attribute__((address_space(3))) void*)(lp), 16, 0, 0)
#define MEMFENCE asm volatile("" ::: "memory")

// ---------- kernel 3b: 256x256 8-phase, BK=64, 512 thr (8 waves 2Mx4N)
// Register-pipelined fragment reads: each phase's ds_reads are issued one
// phase early so their latency hides under the previous MFMA cluster.
// C[M,N] = (A[M,K]bf16 . B[N,K]^T) * alpha[n] + bias[n]
__global__ __launch_bounds__(512, 2) void k_gemm256(
    const unsigned short* __restrict__ A, const unsigned short* __restrict__ B,
    const float* __restrict__ alpha, const float* __restrict__ bias,
    float* __restrict__ C, int M, int N, int K, int tm, int tn) {
  // [buf(2)][A/B][256 rows][64 cols] bf16 = 128 KiB
  __shared__ __attribute__((aligned(128))) unsigned short lds[65536];

  const int nwg = tm * tn;
  int bid = blockIdx.x;
  if ((nwg & 7) == 0) bid = (bid & 7) * (nwg >> 3) + (bid >> 3);  // XCD chunked swizzle
  const int mT = bid % tm;  // m-major: consecutive blocks share B-panel (L2)
  const int nT = bid / tm;
  const long m0 = (long)mT * 256;
  const int n0 = nT * 256;

  const int tid = threadIdx.x;
  const int lane = tid & 63;
  const int w = tid >> 6;
  const int wr = w >> 2;
  const int wc = w & 3;
  const int lr = lane & 15;
  const int l16 = lane >> 4;

  // staging: 8 waves x 64 lanes x 16B = 64 rows of 128B per GLDS pair-half.
  // LDS dest linear; global source pre-swizzled: LDS(r,s) = global(r, s^(r&7)).
  const int srow = (w << 3) + (lane >> 3);
  const int sslot = (lane & 7) ^ (lane >> 3);
  const unsigned short* gA0 = A + (size_t)(m0 + srow) * K + sslot * 8;
  const unsigned short* gB0 = B + (size_t)(n0 + srow) * K + sslot * 8;
  const int sbase = (w << 9);

#define STAGE_A(bufo, t_, h_)                                                   \
  do {                                                                          \
    const unsigned short* g = gA0 + (size_t)((h_)*128) * K + (size_t)(t_) * 64; \
    unsigned short* l = lds + (bufo) + (h_)*8192 + sbase;                       \
    GLDS(g, l);                                                                 \
    GLDS(g + (size_t)64 * K, l + 4096);                                         \
  } while (0)
#define STAGE_B(bufo, t_, h_)                                                   \
  do {                                                                          \
    const unsigned short* g = gB0 + (size_t)((h_)*128) * K + (size_t)(t_) * 64; \
    unsigned short* l = lds + (bufo) + 16384 + (h_)*8192 + sbase;               \
    GLDS(g, l);                                                                 \
    GLDS(g + (size_t)64 * K, l + 4096);                                         \
  } while (0)
#define FRAG(off) (*reinterpret_cast<const bf16x8_t*>(&lds[off]))

  // swizzled fragment addressing: logical (row, slot) -> LDS slot^(row&7)
  const int sx = lr & 7;
  const int sk0 = ((0 + l16) ^ sx) * 8;  // kk=0
  const int sk1 = ((4 + l16) ^ sx) * 8;  // kk=1
  const int rA = (wr * 16 + lr) * 64;    // +i*32 rows -> +i*2048
  const int rB = (wc * 16 + lr) * 64;    // +j*64 rows -> +j*4096

  f32x4 acc[8][4];
#pragma unroll
  for (int i = 0; i < 8; ++i)
#pragma unroll
    for (int j = 0; j < 4; ++j) acc[i][j] = (f32x4){0.f, 0.f, 0.f, 0.f};
  bf16x8_t aL[4][2], aH[4][2], bL[2][2], bH[2][2];

  const int NT = K >> 6;

  // ---- prologue: stage T0 fully + T1.A0/B0 (4 loads left in flight)
  STAGE_A(0, 0, 0);
  STAGE_B(0, 0, 0);
  STAGE_B(0, 0, 1);
  STAGE_A(0, 0, 1);
  STAGE_A(32768, 1, 0);
  STAGE_B(32768, 1, 0);
  asm volatile("s_waitcnt vmcnt(4)" ::: "memory");
  __builtin_amdgcn_s_barrier();
  // initial frag reads for p1 of t=0 (A-lo, B-lo of buf0)
#pragma unroll
  for (int i = 0; i < 4; ++i) {
    aL[i][0] = FRAG(rA + i * 2048 + sk0);
    aL[i][1] = FRAG(rA + i * 2048 + sk1);
  }
#pragma unroll
  for (int j = 0; j < 2; ++j) {
    bL[j][0] = FRAG(16384 + rB + j * 4096 + sk0);
    bL[j][1] = FRAG(16384 + rB + j * 4096 + sk1);
  }

  for (int t = 0; t < NT; ++t) {
    const int cur = (t & 1) << 15;
    const int oth = cur ^ 32768;

    // ---- p1: issue bH reads (consumed p2); stage (T+1).B1; MFMA q(Alo,Blo)
#pragma unroll
    for (int j = 0; j < 2; ++j) {
      bH[j][0] = FRAG(cur + 16384 + rB + (j + 2) * 4096 + sk0);
      bH[j][1] = FRAG(cur + 16384 + rB + (j + 2) * 4096 + sk1);
    }
    if (t + 1 < NT) STAGE_B(oth, t + 1, 1);
    __builtin_amdgcn_s_barrier();
    __builtin_amdgcn_s_setprio(1);
#pragma unroll
    for (int i = 0; i < 4; ++i)
#pragma unroll
      for (int j = 0; j < 2; ++j) {
        acc[i][j] = __builtin_amdgcn_mfma_f32_16x16x32_bf16(aL[i][0], bL[j][0], acc[i][j], 0, 0, 0);
        acc[i][j] = __builtin_amdgcn_mfma_f32_16x16x32_bf16(aL[i][1], bL[j][1], acc[i][j], 0, 0, 0);
      }
    __builtin_amdgcn_s_setprio(0);
    __builtin_amdgcn_s_barrier();
    MEMFENCE;

    // ---- p2: issue aH reads (consumed p3); stage (T+1).A1; MFMA q(Alo,Bhi)
#pragma unroll
    for (int i = 0; i < 4; ++i) {
      aH[i][0] = FRAG(cur + rA + (i + 4) * 2048 + sk0);
      aH[i][1] = FRAG(cur + rA + (i + 4) * 2048 + sk1);
    }
    if (t + 1 < NT) STAGE_A(oth, t + 1, 1);
    __builtin_amdgcn_s_barrier();
    __builtin_amdgcn_s_setprio(1);
#pragma unroll
    for (int i = 0; i < 4; ++i)
#pragma unroll
      for (int j = 0; j < 2; ++j) {
        acc[i][j + 2] = __builtin_amdgcn_mfma_f32_16x16x32_bf16(aL[i][0], bH[j][0], acc[i][j + 2], 0, 0, 0);
        acc[i][j + 2] = __builtin_amdgcn_mfma_f32_16x16x32_bf16(aL[i][1], bH[j][1], acc[i][j + 2], 0, 0, 0);
      }
    __builtin_amdgcn_s_setprio(0);
    __builtin_amdgcn_s_barrier();
    MEMFENCE;

    // ---- p3: stage (T+2).A0; MFMA q(Ahi,Blo)
    if (t + 2 < NT) STAGE_A(cur, t + 2, 0);
    __builtin_amdgcn_s_barrier();
    __builtin_amdgcn_s_setprio(1);
#pragma unroll
    for (int i = 0; i < 4; ++i)
#pragma unroll
      for (int j = 0; j < 2; ++j) {
        acc[i + 4][j] = __builtin_amdgcn_mfma_f32_16x16x32_bf16(aH[i][0], bL[j][0], acc[i + 4][j], 0, 0, 0);
        acc[i + 4][j] = __builtin_amdgcn_mfma_f32_16x16x32_bf16(aH[i][1], bL[j][1], acc[i + 4][j], 0, 0, 0);
      }
    __builtin_amdgcn_s_setprio(0);
    __builtin_amdgcn_s_barrier();
    MEMFENCE;

    // ---- p4: stage (T+2).B0; counted vmcnt; issue next-iter aL/bL reads
    //          (safe only after the vmcnt guarantee); MFMA q(Ahi,Bhi)
    if (t + 2 < NT) {
      STAGE_B(cur, t + 2, 0);
      asm volatile("s_waitcnt vmcnt(4)" ::: "memory");  // (T+1) fully landed
    } else {
      asm volatile("s_waitcnt vmcnt(0)" ::: "memory");
    }
    __builtin_amdgcn_s_barrier();
    if (t + 1 < NT) {
#pragma unroll
      for (int i = 0; i < 4; ++i) {
        aL[i][0] = FRAG(oth + rA + i * 2048 + sk0);
        aL[i][1] = FRAG(oth + rA + i * 2048 + sk1);
      }
#pragma unroll
      for (int j = 0; j < 2; ++j) {
        bL[j][0] = FRAG(oth + 16384 + rB + j * 4096 + sk0);
        bL[j][1] = FRAG(oth + 16384 + rB + j * 4096 + sk1);
      }
    }
    __builtin_amdgcn_s_setprio(1);
#pragma unroll
    for (int i = 0; i < 4; ++i)
#pragma unroll
      for (int j = 0; j < 2; ++j) {
        acc[i + 4][j + 2] = __builtin_amdgcn_mfma_f32_16x16x32_bf16(aH[i][0], bH[j][0], acc[i + 4][j + 2], 0, 0, 0);
        acc[i + 4][j + 2] = __builtin_amdgcn_mfma_f32_16x16x32_bf16(aH[i][1], bH[j][1], acc[i + 4][j + 2], 0, 0, 0);
      }
    __builtin_amdgcn_s_setprio(0);
    __builtin_amdgcn_s_barrier();
    MEMFENCE;
  }

  // ---- epilogue: C/D frag layout col=lane&15, row=(lane>>4)*4+r [m89]
#pragma unroll
  for (int j = 0; j < 4; ++j) {
    const int col = n0 + j * 64 + wc * 16 + lr;
    const float al = alpha[col];
    const float bi = bias[col];
#pragma unroll
    for (int i = 0; i < 8; ++i) {
      const long row = m0 + i * 32 + wr * 16 + l16 * 4;
      f32x4 v = acc[i][j];
#pragma unroll
      for (int r = 0; r < 4; ++r) C[(size_t)(row + r) * N + col] = v[r] * al + bi;
    }
  }
#undef STAGE_A
#undef STAGE_B
#undef FRAG
}

// ---------- kernel 3a: verified 128x128 2-phase fallback (round-0, passed)
__global__ __launch_bounds__(256) void k_gemm(
    const unsigned short* __restrict__ A, const unsigned short* __restrict__ B,
    const float* __restrict__ alpha, const float* __restrict__ bias,
    float* __restrict__ C, int M, int N, int K, int tm) {
  __shared__ unsigned short tA[128 * 32];
  __shared__ unsigned short tB[128 * 32];
  const int bid = blockIdx.x;
  const int mT = bid % tm;
  const int nT = bid / tm;
  const int m0 = mT * 128, n0 = nT * 128;
  const int tid = threadIdx.x;
  const int lane = tid & 63;
  const int wid = tid >> 6;
  const int wr = wid >> 1, wc = wid & 1;
  f32x4 acc[4][4];
#pragma unroll
  for (int i = 0; i < 4; ++i)
#pragma unroll
    for (int j = 0; j < 4; ++j) acc[i][j] = (f32x4){0.f, 0.f, 0.f, 0.f};
  const int srow = wid * 16 + (lane >> 2);
  const int scol = (lane & 3) * 8;
  const unsigned short* gA0 = A + (size_t)(m0 + srow) * K + scol;
  const unsigned short* gA1 = A + (size_t)(m0 + 64 + srow) * K + scol;
  const unsigned short* gB0 = B + (size_t)(n0 + srow) * K + scol;
  const unsigned short* gB1 = B + (size_t)(n0 + 64 + srow) * K + scol;
  unsigned short* lA0 = tA + wid * 512;
  unsigned short* lA1 = tA + 2048 + wid * 512;
  unsigned short* lB0 = tB + wid * 512;
  unsigned short* lB1 = tB + 2048 + wid * 512;
  const int lr = lane & 15;
  const int kb = lane >> 4;
  int aoff[4], boff[4];
#pragma unroll
  for (int i = 0; i < 4; ++i) {
    aoff[i] = (wr * 64 + i * 16 + lr) * 32 + kb * 8;
    boff[i] = (wc * 64 + i * 16 + lr) * 32 + kb * 8;
  }
  for (int k0 = 0; k0 < K; k0 += 32) {
    __syncthreads();
    GLDS(gA0 + k0, lA0);
    GLDS(gA1 + k0, lA1);
    GLDS(gB0 + k0, lB0);
    GLDS(gB1 + k0, lB1);
    __syncthreads();
    bf16x8_t af[4], bfr[4];
#pragma unroll
    for (int i = 0; i < 4; ++i) af[i] = *reinterpret_cast<const bf16x8_t*>(&tA[aoff[i]]);
#pragma unroll
    for (int j = 0; j < 4; ++j) bfr[j] = *reinterpret_cast<const bf16x8_t*>(&tB[boff[j]]);
#pragma unroll
    for (int i = 0; i < 4; ++i)
#pragma unroll
      for (int j = 0; j < 4; ++j)
        acc[i][j] = __builtin_amdgcn_mfma_f32_16x16x32_bf16(af[i], bfr[j], acc[i][j], 0, 0, 0);
  }
#pragma unroll
  for (int j = 0; j < 4; ++j) {
    const int col = n0 + wc * 64 + j * 16 + lr;
    const float al = alpha[col];
    const float bi = bias[col];
#pragma unroll
    for (int i = 0; i < 4; ++i) {
      const int row = m0 + wr * 64 + i * 16 + kb * 4;
      f32x4 v = acc[i][j];
#pragma unroll
      for (int r = 0; r < 4; ++r) C[(size_t)(row + r) * N + col] = v[r] * al + bi;
    }
  }
}

// ---------- fallback: slow but correct, zero scratch
__global__ void k_naive(const float* __restrict__ x, const float* __restrict__ W,
                        const float* __restrict__ bias, float* __restrict__ out,
                        int M, int N, int K) {
  int m = blockIdx.x;
  int n = blockIdx.y * 256 + threadIdx.x;
  if (n >= N) return;
  const float* xr = x + (size_t)m * K;
  const float* wr = W + (size_t)n * K;
  float sa = 0.f, s = 0.f;
  for (int i = 0; i < K; ++i) {
    float wv = wr[i];
    sa += fabsf(wv);
    float sg = (wv > 0.f) ? 1.f : ((wv < 0.f) ? -1.f : 0.f);
    s += xr[i] * sg;
  }
  out[(size_t)m * N + n] = (sa / (float)K) * s + bias[n];
}

extern "C" void kernel_launch(void* const* d_in, const int* in_sizes, int n_in,
                              void* d_out, int out_size, void* d_ws, size_t ws_size,
                              hipStream_t stream) {
  const float* x = (const float*)d_in[0];
  const float* w = (const float*)d_in[1];
  const float* bias = (const float*)d_in[2];
  float* out = (float*)d_out;

  const int D_OUT = in_sizes[2];
  const int D_IN = in_sizes[1] / D_OUT;
  const long long M = (long long)in_sizes[0] / D_IN;
  const int N = D_OUT, K = D_IN;

  const size_t xbB = (size_t)M * K * 2;
  const size_t wbB = (size_t)N * K * 2;
  const size_t need = xbB + wbB + (size_t)N * 4;

  const bool prep_ok = (ws_size >= need) && (K % 1024 == 0) && ((M * K) % 4 == 0);
  const bool f256 = prep_ok && (M % 256 == 0) && (N % 256 == 0) && (K >= 128);
  const bool f128 = prep_ok && (M % 128 == 0) && (N % 128 == 0) && (K % 32 == 0);

  if (f256 || f128) {
    unsigned short* xb = (unsigned short*)d_ws;
    unsigned short* wb = (unsigned short*)((char*)d_ws + xbB);
    float* alpha = (float*)((char*)d_ws + xbB + wbB);
    k_prep_w<<<N, 256, 0, stream>>>(w, wb, alpha, K);
    long long n4 = M * (long long)K / 4;
    k_conv_x<<<2048, 256, 0, stream>>>(x, xb, n4);
    bool done = false;
    if (f256) {
      const int tm = (int)(M / 256), tn = N / 256;
      k_gemm256<<<tm * tn, 512, 0, stream>>>(xb, wb, alpha, bias, out, (int)M, N, K, tm, tn);
      done = (hipGetLastError() == hipSuccess);
    }
    if (!done) {
      const int tm = (int)(M / 128), tn = N / 128;
      k_gemm<<<tm * tn, 256, 0, stream>>>(xb, wb, alpha, bias, out, (int)M, N, K, tm);
    }
  } else {
    dim3 g((unsigned)M, (unsigned)((N + 255) / 256));
    k_naive<<<g, 256, 0, stream>>>(x, w, bias, out, (int)M, N, K);
  }
}

// Round 4
// 287.712 us; speedup vs baseline: 1.0710x; 1.0710x over previous
//
#include <hip/hip_runtime.h>
#include <hip/hip_bf16.h>
#include <stdint.h>

typedef __bf16 bf16x8_t __attribute__((ext_vector_type(8)));
typedef float f32x4 __attribute__((ext_vector_type(4)));

__device__ __forceinline__ unsigned short f2bf_rne(float f) {
  unsigned int u = __float_as_uint(f);
  u += 0x7FFFu + ((u >> 16) & 1u);
  return (unsigned short)(u >> 16);
}

// ---------- kernel 1: alpha[o] = mean|W[o,:]|, wb[o,:] = sign(W[o,:]) as bf16 bits
__global__ __launch_bounds__(256) void k_prep_w(const float* __restrict__ W,
                                                unsigned short* __restrict__ wb,
                                                float* __restrict__ alpha, int K) {
  const int o = blockIdx.x;
  const float* row = W + (size_t)o * K;
  unsigned short* orow = wb + (size_t)o * K;
  const int tid = threadIdx.x;
  float s = 0.f;
  const int nj = K / 1024;
  for (int j = 0; j < nj; ++j) {
    int base = j * 1024 + tid * 4;
    float4 v = *reinterpret_cast<const float4*>(row + base);
    s += fabsf(v.x) + fabsf(v.y) + fabsf(v.z) + fabsf(v.w);
    ushort4 sg;
    sg.x = v.x > 0.f ? 0x3F80u : (v.x < 0.f ? 0xBF80u : 0u);
    sg.y = v.y > 0.f ? 0x3F80u : (v.y < 0.f ? 0xBF80u : 0u);
    sg.z = v.z > 0.f ? 0x3F80u : (v.z < 0.f ? 0xBF80u : 0u);
    sg.w = v.w > 0.f ? 0x3F80u : (v.w < 0.f ? 0xBF80u : 0u);
    *reinterpret_cast<ushort4*>(orow + base) = sg;
  }
  for (int off = 32; off > 0; off >>= 1) s += __shfl_down(s, off);
  __shared__ float red[4];
  int lane = tid & 63, wid = tid >> 6;
  if (lane == 0) red[wid] = s;
  __syncthreads();
  if (tid == 0) alpha[o] = (red[0] + red[1] + red[2] + red[3]) / (float)K;
}

// ---------- kernel 2: x fp32 -> bf16 (RNE)
__global__ __launch_bounds__(256) void k_conv_x(const float* __restrict__ x,
                                                unsigned short* __restrict__ xb,
                                                long long n4) {
  long long i = (long long)blockIdx.x * blockDim.x + threadIdx.x;
  const long long stride = (long long)gridDim.x * blockDim.x;
  for (; i < n4; i += stride) {
    float4 v = reinterpret_cast<const float4*>(x)[i];
    ushort4 o;
    o.x = f2bf_rne(v.x);
    o.y = f2bf_rne(v.y);
    o.z = f2bf_rne(v.z);
    o.w = f2bf_rne(v.w);
    reinterpret_cast<ushort4*>(xb)[i] = o;
  }
}

#define GLDS(gp, lp)                                                                   \
  __builtin_amdgcn_global_load_lds((const __attribute__((address_space(1))) void*)(gp),\
                                   (__attribute__((address_space(3))) void*)(lp), 16, 0, 0)

// ---------- kernel 3b: 256x256, m201-faithful 8-phase / 2-K-tile unrolled loop.
// buf0 = even K-tiles (LDS offset 0), buf1 = odd K-tiles (offset 32768): all LDS
// offsets compile-time. One half-tile staged per phase; vmcnt(6) at p4/p8 only.
// C[M,N] = (A[M,K]bf16 . B[N,K]^T) * alpha[n] + bias[n]
__global__ __launch_bounds__(512, 2) void k_gemm256(
    const unsigned short* __restrict__ A, const unsigned short* __restrict__ B,
    const float* __restrict__ alpha, const float* __restrict__ bias,
    float* __restrict__ C, int M, int N, int K, int tm, int tn) {
  // [buf(2)][A/B][256 rows][64 cols] bf16 = 128 KiB
  __shared__ __attribute__((aligned(128))) unsigned short lds[65536];

  const int nwg = tm * tn;
  int bid = blockIdx.x;
  if ((nwg & 7) == 0) bid = (bid & 7) * (nwg >> 3) + (bid >> 3);  // XCD chunked swizzle
  const int mT = bid % tm;  // m-major: consecutive blocks share B-panel (L2)
  const int nT = bid / tm;
  const long m0 = (long)mT * 256;
  const int n0 = nT * 256;

  const int tid = threadIdx.x;
  const int lane = tid & 63;
  const int w = tid >> 6;
  const int wr = w >> 2;
  const int wc = w & 3;
  const int lr = lane & 15;
  const int l16 = lane >> 4;

  // staging: 8 waves x 64 lanes x 16B = 64 rows of 128B per GLDS.
  // LDS dest linear; global source pre-swizzled: LDS(r,s) = global(r, s^(r&7)).
  const int srow = (w << 3) + (lane >> 3);
  const int sslot = (lane & 7) ^ (lane >> 3);
  const unsigned short* gA0 = A + (size_t)(m0 + srow) * K + sslot * 8;
  const unsigned short* gB0 = B + (size_t)(n0 + srow) * K + sslot * 8;
  const int sbase = (w << 9);

#define STAGE_A(bufo, t_, h_)                                                   \
  do {                                                                          \
    const unsigned short* g = gA0 + (size_t)((h_)*128) * K + (size_t)(t_) * 64; \
    unsigned short* l = lds + (bufo) + (h_)*8192 + sbase;                       \
    GLDS(g, l);                                                                 \
    GLDS(g + (size_t)64 * K, l + 4096);                                         \
  } while (0)
#define STAGE_B(bufo, t_, h_)                                                   \
  do {                                                                          \
    const unsigned short* g = gB0 + (size_t)((h_)*128) * K + (size_t)(t_) * 64; \
    unsigned short* l = lds + (bufo) + 16384 + (h_)*8192 + sbase;               \
    GLDS(g, l);                                                                 \
    GLDS(g + (size_t)64 * K, l + 4096);                                         \
  } while (0)
#define FRAG(off) (*reinterpret_cast<const bf16x8_t*>(&lds[off]))
#define BAR __builtin_amdgcn_s_barrier()

  // per-lane frag base offsets (constant part folds into ds offset: immediates)
  const int sx = lr & 7;
  const int pA0 = (wr * 16 + lr) * 64 + ((0 + l16) ^ sx) * 8;          // kk=0
  const int pA1 = (wr * 16 + lr) * 64 + ((4 + l16) ^ sx) * 8;          // kk=1
  const int pB0 = 16384 + (wc * 16 + lr) * 64 + ((0 + l16) ^ sx) * 8;  // kk=0
  const int pB1 = 16384 + (wc * 16 + lr) * 64 + ((4 + l16) ^ sx) * 8;  // kk=1

  f32x4 acc[8][4];
#pragma unroll
  for (int i = 0; i < 8; ++i)
#pragma unroll
    for (int j = 0; j < 4; ++j) acc[i][j] = (f32x4){0.f, 0.f, 0.f, 0.f};
  bf16x8_t aL[4][2], aH[4][2], bL[2][2], bH[2][2];

  const int NT = K >> 6;       // K-tiles (even, >= 2)
  const int NIT = NT >> 1;     // 8-phase iterations

  auto rdAL = [&](int BUF) {
#pragma unroll
    for (int i = 0; i < 4; ++i) {
      aL[i][0] = FRAG(BUF + pA0 + i * 2048);
      aL[i][1] = FRAG(BUF + pA1 + i * 2048);
    }
  };
  auto rdAH = [&](int BUF) {
#pragma unroll
    for (int i = 0; i < 4; ++i) {
      aH[i][0] = FRAG(BUF + pA0 + (i + 4) * 2048);
      aH[i][1] = FRAG(BUF + pA1 + (i + 4) * 2048);
    }
  };
  auto rdBL = [&](int BUF) {
#pragma unroll
    for (int j = 0; j < 2; ++j) {
      bL[j][0] = FRAG(BUF + pB0 + j * 4096);
      bL[j][1] = FRAG(BUF + pB1 + j * 4096);
    }
  };
  auto rdBH = [&](int BUF) {
#pragma unroll
    for (int j = 0; j < 2; ++j) {
      bH[j][0] = FRAG(BUF + pB0 + (j + 2) * 4096);
      bH[j][1] = FRAG(BUF + pB1 + (j + 2) * 4096);
    }
  };
  auto Q1 = [&]() {  // acc[0..3][0..1] += aL x bL
    __builtin_amdgcn_s_setprio(1);
#pragma unroll
    for (int i = 0; i < 4; ++i)
#pragma unroll
      for (int j = 0; j < 2; ++j) {
        acc[i][j] = __builtin_amdgcn_mfma_f32_16x16x32_bf16(aL[i][0], bL[j][0], acc[i][j], 0, 0, 0);
        acc[i][j] = __builtin_amdgcn_mfma_f32_16x16x32_bf16(aL[i][1], bL[j][1], acc[i][j], 0, 0, 0);
      }
    __builtin_amdgcn_s_setprio(0);
  };
  auto Q2 = [&]() {  // acc[0..3][2..3] += aL x bH
    __builtin_amdgcn_s_setprio(1);
#pragma unroll
    for (int i = 0; i < 4; ++i)
#pragma unroll
      for (int j = 0; j < 2; ++j) {
        acc[i][j + 2] = __builtin_amdgcn_mfma_f32_16x16x32_bf16(aL[i][0], bH[j][0], acc[i][j + 2], 0, 0, 0);
        acc[i][j + 2] = __builtin_amdgcn_mfma_f32_16x16x32_bf16(aL[i][1], bH[j][1], acc[i][j + 2], 0, 0, 0);
      }
    __builtin_amdgcn_s_setprio(0);
  };
  auto Q3 = [&]() {  // acc[4..7][0..1] += aH x bL
    __builtin_amdgcn_s_setprio(1);
#pragma unroll
    for (int i = 0; i < 4; ++i)
#pragma unroll
      for (int j = 0; j < 2; ++j) {
        acc[i + 4][j] = __builtin_amdgcn_mfma_f32_16x16x32_bf16(aH[i][0], bL[j][0], acc[i + 4][j], 0, 0, 0);
        acc[i + 4][j] = __builtin_amdgcn_mfma_f32_16x16x32_bf16(aH[i][1], bL[j][1], acc[i + 4][j], 0, 0, 0);
      }
    __builtin_amdgcn_s_setprio(0);
  };
  auto Q4 = [&]() {  // acc[4..7][2..3] += aH x bH
    __builtin_amdgcn_s_setprio(1);
#pragma unroll
    for (int i = 0; i < 4; ++i)
#pragma unroll
      for (int j = 0; j < 2; ++j) {
        acc[i + 4][j + 2] = __builtin_amdgcn_mfma_f32_16x16x32_bf16(aH[i][0], bH[j][0], acc[i + 4][j + 2], 0, 0, 0);
        acc[i + 4][j + 2] = __builtin_amdgcn_mfma_f32_16x16x32_bf16(aH[i][1], bH[j][1], acc[i + 4][j + 2], 0, 0, 0);
      }
    __builtin_amdgcn_s_setprio(0);
  };

  // ---- prologue: T0 full (8 loads) + T1.A0/B0/B1 (6 loads); drain T0, keep 6 in flight
  STAGE_A(0, 0, 0);
  STAGE_B(0, 0, 0);
  STAGE_B(0, 0, 1);
  STAGE_A(0, 0, 1);
  STAGE_A(32768, 1, 0);
  STAGE_B(32768, 1, 0);
  STAGE_B(32768, 1, 1);
  asm volatile("s_waitcnt vmcnt(6)" ::: "memory");
  BAR;

  // ---- 8-phase iteration: computes tiles E=2I (buf0) and O=2I+1 (buf1);
  // stages E+2 into buf0 (p2..p5) and O's A1 (p1) + O+2 into buf1 (p6..p8).
  // vmcnt(6) at p4 guarantees all of tile O landed; at p8 all of tile E+2.
  auto iter = [&](int I, bool LAST) {
    const int TO1 = 2 * I + 1, TE2 = 2 * I + 2, TO2 = 2 * I + 3;
    // p1
    rdAL(0); rdBL(0);
    STAGE_A(32768, TO1, 1);
    BAR; Q1(); BAR;
    // p2
    rdBH(0);
    if (!LAST) STAGE_A(0, TE2, 0);
    BAR; Q2(); BAR;
    // p3
    rdAH(0);
    if (!LAST) STAGE_B(0, TE2, 0);
    BAR; Q3(); BAR;
    // p4
    if (!LAST) {
      STAGE_B(0, TE2, 1);
      asm volatile("s_waitcnt vmcnt(6)" ::: "memory");  // tile O fully landed
    } else {
      asm volatile("s_waitcnt vmcnt(0)" ::: "memory");
    }
    BAR; Q4(); BAR;
    // p5
    rdAL(32768); rdBL(32768);
    if (!LAST) STAGE_A(0, TE2, 1);
    BAR; Q1(); BAR;
    // p6
    rdBH(32768);
    if (!LAST) STAGE_A(32768, TO2, 0);
    BAR; Q2(); BAR;
    // p7
    rdAH(32768);
    if (!LAST) STAGE_B(32768, TO2, 0);
    BAR; Q3(); BAR;
    // p8
    if (!LAST) {
      STAGE_B(32768, TO2, 1);
      asm volatile("s_waitcnt vmcnt(6)" ::: "memory");  // tile E+2 fully landed
    }
    BAR; Q4(); BAR;
  };

  for (int I = 0; I < NIT - 1; ++I) iter(I, false);
  iter(NIT - 1, true);

  // ---- epilogue: C/D frag layout col=lane&15, row=(lane>>4)*4+r [m89]
#pragma unroll
  for (int j = 0; j < 4; ++j) {
    const int col = n0 + j * 64 + wc * 16 + lr;
    const float al = alpha[col];
    const float bi = bias[col];
#pragma unroll
    for (int i = 0; i < 8; ++i) {
      const long row = m0 + i * 32 + wr * 16 + l16 * 4;
      f32x4 v = acc[i][j];
#pragma unroll
      for (int r = 0; r < 4; ++r) C[(size_t)(row + r) * N + col] = v[r] * al + bi;
    }
  }
#undef STAGE_A
#undef STAGE_B
#undef FRAG
#undef BAR
}

// ---------- kernel 3a: verified 128x128 2-phase fallback (round-0, passed)
__global__ __launch_bounds__(256) void k_gemm(
    const unsigned short* __restrict__ A, const unsigned short* __restrict__ B,
    const float* __restrict__ alpha, const float* __restrict__ bias,
    float* __restrict__ C, int M, int N, int K, int tm) {
  __shared__ unsigned short tA[128 * 32];
  __shared__ unsigned short tB[128 * 32];
  const int bid = blockIdx.x;
  const int mT = bid % tm;
  const int nT = bid / tm;
  const int m0 = mT * 128, n0 = nT * 128;
  const int tid = threadIdx.x;
  const int lane = tid & 63;
  const int wid = tid >> 6;
  const int wr = wid >> 1, wc = wid & 1;
  f32x4 acc[4][4];
#pragma unroll
  for (int i = 0; i < 4; ++i)
#pragma unroll
    for (int j = 0; j < 4; ++j) acc[i][j] = (f32x4){0.f, 0.f, 0.f, 0.f};
  const int srow = wid * 16 + (lane >> 2);
  const int scol = (lane & 3) * 8;
  const unsigned short* gA0 = A + (size_t)(m0 + srow) * K + scol;
  const unsigned short* gA1 = A + (size_t)(m0 + 64 + srow) * K + scol;
  const unsigned short* gB0 = B + (size_t)(n0 + srow) * K + scol;
  const unsigned short* gB1 = B + (size_t)(n0 + 64 + srow) * K + scol;
  unsigned short* lA0 = tA + wid * 512;
  unsigned short* lA1 = tA + 2048 + wid * 512;
  unsigned short* lB0 = tB + wid * 512;
  unsigned short* lB1 = tB + 2048 + wid * 512;
  const int lr = lane & 15;
  const int kb = lane >> 4;
  int aoff[4], boff[4];
#pragma unroll
  for (int i = 0; i < 4; ++i) {
    aoff[i] = (wr * 64 + i * 16 + lr) * 32 + kb * 8;
    boff[i] = (wc * 64 + i * 16 + lr) * 32 + kb * 8;
  }
  for (int k0 = 0; k0 < K; k0 += 32) {
    __syncthreads();
    GLDS(gA0 + k0, lA0);
    GLDS(gA1 + k0, lA1);
    GLDS(gB0 + k0, lB0);
    GLDS(gB1 + k0, lB1);
    __syncthreads();
    bf16x8_t af[4], bfr[4];
#pragma unroll
    for (int i = 0; i < 4; ++i) af[i] = *reinterpret_cast<const bf16x8_t*>(&tA[aoff[i]]);
#pragma unroll
    for (int j = 0; j < 4; ++j) bfr[j] = *reinterpret_cast<const bf16x8_t*>(&tB[boff[j]]);
#pragma unroll
    for (int i = 0; i < 4; ++i)
#pragma unroll
      for (int j = 0; j < 4; ++j)
        acc[i][j] = __builtin_amdgcn_mfma_f32_16x16x32_bf16(af[i], bfr[j], acc[i][j], 0, 0, 0);
  }
#pragma unroll
  for (int j = 0; j < 4; ++j) {
    const int col = n0 + wc * 64 + j * 16 + lr;
    const float al = alpha[col];
    const float bi = bias[col];
#pragma unroll
    for (int i = 0; i < 4; ++i) {
      const int row = m0 + wr * 64 + i * 16 + kb * 4;
      f32x4 v = acc[i][j];
#pragma unroll
      for (int r = 0; r < 4; ++r) C[(size_t)(row + r) * N + col] = v[r] * al + bi;
    }
  }
}

// ---------- fallback: slow but correct, zero scratch
__global__ void k_naive(const float* __restrict__ x, const float* __restrict__ W,
                        const float* __restrict__ bias, float* __restrict__ out,
                        int M, int N, int K) {
  int m = blockIdx.x;
  int n = blockIdx.y * 256 + threadIdx.x;
  if (n >= N) return;
  const float* xr = x + (size_t)m * K;
  const float* wr = W + (size_t)n * K;
  float sa = 0.f, s = 0.f;
  for (int i = 0; i < K; ++i) {
    float wv = wr[i];
    sa += fabsf(wv);
    float sg = (wv > 0.f) ? 1.f : ((wv < 0.f) ? -1.f : 0.f);
    s += xr[i] * sg;
  }
  out[(size_t)m * N + n] = (sa / (float)K) * s + bias[n];
}

extern "C" void kernel_launch(void* const* d_in, const int* in_sizes, int n_in,
                              void* d_out, int out_size, void* d_ws, size_t ws_size,
                              hipStream_t stream) {
  const float* x = (const float*)d_in[0];
  const float* w = (const float*)d_in[1];
  const float* bias = (const float*)d_in[2];
  float* out = (float*)d_out;

  const int D_OUT = in_sizes[2];
  const int D_IN = in_sizes[1] / D_OUT;
  const long long M = (long long)in_sizes[0] / D_IN;
  const int N = D_OUT, K = D_IN;

  const size_t xbB = (size_t)M * K * 2;
  const size_t wbB = (size_t)N * K * 2;
  const size_t need = xbB + wbB + (size_t)N * 4;

  const bool prep_ok = (ws_size >= need) && (K % 1024 == 0) && ((M * K) % 4 == 0);
  const bool f256 = prep_ok && (M % 256 == 0) && (N % 256 == 0) && (K % 128 == 0);
  const bool f128 = prep_ok && (M % 128 == 0) && (N % 128 == 0) && (K % 32 == 0);

  if (f256 || f128) {
    unsigned short* xb = (unsigned short*)d_ws;
    unsigned short* wb = (unsigned short*)((char*)d_ws + xbB);
    float* alpha = (float*)((char*)d_ws + xbB + wbB);
    k_prep_w<<<N, 256, 0, stream>>>(w, wb, alpha, K);
    long long n4 = M * (long long)K / 4;
    k_conv_x<<<2048, 256, 0, stream>>>(x, xb, n4);
    bool done = false;
    if (f256) {
      const int tm = (int)(M / 256), tn = N / 256;
      k_gemm256<<<tm * tn, 512, 0, stream>>>(xb, wb, alpha, bias, out, (int)M, N, K, tm, tn);
      done = (hipGetLastError() == hipSuccess);
    }
    if (!done) {
      const int tm = (int)(M / 128), tn = N / 128;
      k_gemm<<<tm * tn, 256, 0, stream>>>(xb, wb, alpha, bias, out, (int)M, N, K, tm);
    }
  } else {
    dim3 g((unsigned)M, (unsigned)((N + 255) / 256));
    k_naive<<<g, 256, 0, stream>>>(x, w, bias, out, (int)M, N, K);
  }
}